// Round 5
// baseline (775.068 us; speedup 1.0000x reference)
//
#include <hip/hip_runtime.h>
#include <math.h>

#define NCH 32
#define CHV (64*32*64)      // one channel volume
#define NB 4
#define NTI 128             // tiles per n: 16 z-tiles x 8 y-tiles
#define INVC (1.0f/(32.0f+1e-6f))
#define D2R 0.017453292519943295f
#define R2D 57.29577951308232f

// LDS slab geometry (pitch 68: +4 zeroed pad cols -> free x-edges)
#define P0 68
#define F0SZ 2448           // 6z * 6y * 68   (612 float4 chunks)
#define F1SZ 2720           // 10z * 4y * 68  (680 chunks)
#define F0B 4               // L[0..3] zero guard
#define F1B (4 + F0SZ)      // 2452, 16B-aligned
#define BUFSZ (4 + F0SZ + F1SZ)   // 5172 floats per buffer (20.7 KB)
#define NCK 1292            // total float4 chunks per channel

// ---------------------------------------------------------------------------
// Kernel 1: fused rotate-warp(feat1) x 27-offset correlation vs feat0.
// Block = (b, 4z x 4y x 64x tile, channel-half): 384 threads (6 waves),
// waves {0,1}->rot0, {2,3}->rot1(identity), {4,5}->rot2. Thread owns 2z x 4x.
// 3 blocks/CU co-resident; double-buffered LDS; edges via shuffles.
// ---------------------------------------------------------------------------
__global__ __launch_bounds__(384, 5) void k_heat(const float* __restrict__ feat0,
                                                 const float* __restrict__ feat1,
                                                 float* __restrict__ partial)
{
    __shared__ float L[2][BUFSZ];
    __shared__ float red[6][27];

    // XCD-chunked remap: each XCD gets 128 consecutive nids (same b, z-adjacent)
    const int lid = (int)blockIdx.x;               // 0..1023
    const int nid = (lid & 7) * 128 + (lid >> 3);
    const int b   = nid >> 8;
    const int rr_ = nid & 255;
    const int zt  = rr_ >> 4;                      // 0..15
    const int yt  = (rr_ >> 1) & 7;                // 0..7
    const int chh = rr_ & 1;                       // channel half

    const int tid = (int)threadIdx.x;
    const int wv = tid >> 6;            // 0..5
    const int lane = tid & 63;
    const int rot = wv >> 1;            // 0,1,2
    const int ww = wv & 1;              // z-pair within rotation group
    const int tx = lane & 15, ty = lane >> 4;
    const int z0 = 4 * zt + 2 * ww;     // owns z0, z0+1
    const int x0 = 4 * tx;

    if (tid < 8) L[tid >> 2][tid & 3] = 0.0f;   // zero guards

    const float th = 4.0f * (float)(rot - 1) * D2R;
    const float cs = cosf(th), sn = sinf(th);

    // ---- bilinear setup (channel-invariant); rot==1 never uses it ----
    float WX0[2][4], WX1[2][4], WZ0[2][4];
    int A1[2][4];
    #pragma unroll
    for (int j = 0; j < 2; ++j) {
        #pragma unroll
        for (int i = 0; i < 4; ++i) {
            const float rx = (float)(x0 + i) - 31.5f;
            const float rz = (float)(z0 + j) - 31.5f;
            const float sx = cs * rx - sn * rz + 31.5f;
            const float sz = sn * rx + cs * rz + 31.5f;
            const float xf = floorf(sx), zf = floorf(sz);
            const float fx = sx - xf, fz = sz - zf;
            const int ix = (int)xf, iz = (int)zf;
            WX0[j][i] = ((unsigned)ix < 64u) ? (1.0f - fx) : 0.0f;
            WX1[j][i] = ((unsigned)(ix + 1) < 64u) ? fx : 0.0f;
            WZ0[j][i] = 1.0f - fz;      // z-OOB rows staged as zeros
            int zl = iz - (4 * zt - 3);
            zl = min(max(zl, 0), 8);
            const int bx = min(max(ix, -1), 63);
            A1[j][i] = F1B + (zl * 4 + ty) * P0 + bx;
        }
    }
    const int A1r1 = F1B + ((2 * ww + 3) * 4 + ty) * P0 + x0;   // identity rows

    // ---- staging map: 1292 chunks, thread t takes f = t + 384k ----
    const float* f0b_ = feat0 + ((size_t)b * NCH + 16 * chh) * CHV;
    const float* f1b_ = feat1 + ((size_t)b * NCH + 16 * chh) * CHV;
    const float* gp[4];
    float gmask[4];
    int wof[4];
    const int nld = (tid < 140) ? 4 : 3;
    #pragma unroll
    for (int k = 0; k < 4; ++k) {
        const int f = tid + 384 * k;
        wof[k] = 4 + 4 * f;
        gmask[k] = 0.0f;
        gp[k] = f0b_;
        if (f < NCK) {
            if (f < 612) {              // feat0 slab [6][6][68], z/y halo -1
                const int q = 4 * f;
                const int zr = q / 408; const int rem = q - zr * 408;
                const int yr = rem / 68; const int x = rem - yr * 68;
                const int zs = 4 * zt - 1 + zr, ys = 4 * yt - 1 + yr;
                const int ok = (x < 64) & (zs >= 0) & (zs < 64)
                             & (ys >= 0) & (ys < 32);
                gp[k] = f0b_ + (ok ? (zs * 2048 + ys * 64 + x) : 0);
                gmask[k] = ok ? 1.0f : 0.0f;
            } else {                    // feat1 slab [10][4][68], z halo -3
                const int q = 4 * f - F0SZ;
                const int zr = q / 272; const int rem = q - zr * 272;
                const int yr = rem / 68; const int x = rem - yr * 68;
                const int zs = 4 * zt - 3 + zr, ys = 4 * yt + yr;
                const int ok = (x < 64) & (zs >= 0) & (zs < 64);
                gp[k] = f1b_ + (ok ? (zs * 2048 + ys * 64 + x) : 0);
                gmask[k] = ok ? 1.0f : 0.0f;
            }
        }
    }

    const int rw = F0B + (2 * ww * 6 + ty) * P0 + x0;   // feat0 corr row base

    float acc[27];
    #pragma unroll
    for (int o = 0; o < 27; ++o) acc[o] = 0.0f;

    // ---- prologue: stage first channel into buffer 0 ----
    {
        float4 vv[4];
        #pragma unroll
        for (int k = 0; k < 4; ++k) if (k < nld) vv[k] = *(const float4*)gp[k];
        #pragma unroll
        for (int k = 0; k < 4; ++k) gp[k] += CHV;
        #pragma unroll
        for (int k = 0; k < 4; ++k) if (k < nld) {
            float4 v = vv[k]; const float m = gmask[k];
            v.x *= m; v.y *= m; v.z *= m; v.w *= m;
            *(float4*)&L[0][wof[k]] = v;
        }
    }
    __syncthreads();

    #pragma unroll 1
    for (int ch = 0; ch < 16; ++ch) {
        const float* Lb = &L[ch & 1][0];

        // issue next channel's loads first (latency hides under compute)
        float4 nv[4];
        if (ch + 1 < 16) {
            #pragma unroll
            for (int k = 0; k < 4; ++k) if (k < nld) nv[k] = *(const float4*)gp[k];
            #pragma unroll
            for (int k = 0; k < 4; ++k) gp[k] += CHV;
        }

        // ---- warp-sample 8 positions ----
        float fa[4], fb[4];
        if (rot == 1) {                 // identity: direct aligned rows
            const float4 a4 = *(const float4*)&Lb[A1r1];
            const float4 b4 = *(const float4*)&Lb[A1r1 + 4 * P0];
            fa[0] = a4.x; fa[1] = a4.y; fa[2] = a4.z; fa[3] = a4.w;
            fb[0] = b4.x; fb[1] = b4.y; fb[2] = b4.z; fb[3] = b4.w;
        } else {
            #pragma unroll
            for (int j = 0; j < 2; ++j) {
                #pragma unroll
                for (int i = 0; i < 4; ++i) {
                    const int a = A1[j][i];
                    const float p00 = Lb[a], p01 = Lb[a + 1];
                    const float p10 = Lb[a + 4 * P0], p11 = Lb[a + 4 * P0 + 1];
                    const float w0 = WZ0[j][i];
                    const float t = w0 * p00 + (1.0f - w0) * p10;
                    const float u = w0 * p01 + (1.0f - w0) * p11;
                    const float v_ = WX0[j][i] * t + WX1[j][i] * u;
                    if (j == 0) fa[i] = v_; else fb[i] = v_;
                }
            }
        }

        // ---- correlation: 12 feat0 rows; x-edges via wave shuffles ----
        #pragma unroll
        for (int yri = 0; yri < 3; ++yri) {
            #pragma unroll
            for (int zri = 0; zri < 4; ++zri) {
                const int off = zri * 408 + yri * 68;
                const float4 m4 = *(const float4*)&Lb[rw + off];
                const float e0s = __shfl_up(m4.w, 1, 64);
                const float e1s = __shfl_down(m4.x, 1, 64);
                const float e0 = (tx == 0) ? 0.0f : e0s;
                const float e1 = (tx == 15) ? 0.0f : e1s;
                const int oy1 = 2 - yri;
                if (zri <= 2) {         // owned z0: oz+1 = 2-zri
                    const int ob = (2 - zri) * 9 + oy1 * 3;
                    acc[ob + 0] += fa[0] * m4.y + fa[1] * m4.z + fa[2] * m4.w + fa[3] * e1;
                    acc[ob + 1] += fa[0] * m4.x + fa[1] * m4.y + fa[2] * m4.z + fa[3] * m4.w;
                    acc[ob + 2] += fa[0] * e0   + fa[1] * m4.x + fa[2] * m4.y + fa[3] * m4.z;
                }
                if (zri >= 1) {         // owned z0+1: oz+1 = 3-zri
                    const int ob = (3 - zri) * 9 + oy1 * 3;
                    acc[ob + 0] += fb[0] * m4.y + fb[1] * m4.z + fb[2] * m4.w + fb[3] * e1;
                    acc[ob + 1] += fb[0] * m4.x + fb[1] * m4.y + fb[2] * m4.z + fb[3] * m4.w;
                    acc[ob + 2] += fb[0] * e0   + fb[1] * m4.x + fb[2] * m4.y + fb[3] * m4.z;
                }
            }
        }

        // ---- write next channel into the other buffer ----
        if (ch + 1 < 16) {
            float* Ln = &L[(ch + 1) & 1][0];
            #pragma unroll
            for (int k = 0; k < 4; ++k) if (k < nld) {
                float4 v = nv[k]; const float m = gmask[k];
                v.x *= m; v.y *= m; v.z *= m; v.w *= m;
                *(float4*)&Ln[wof[k]] = v;
            }
        }
        __syncthreads();
    }

    // ---- reduction (fixed order -> deterministic) ----
    #pragma unroll 1
    for (int o = 0; o < 27; ++o) {
        float v = acc[o];
        #pragma unroll
        for (int d = 32; d >= 1; d >>= 1) v += __shfl_down(v, d, 64);
        if (lane == 0) red[wv][o] = v;
    }
    __syncthreads();
    if (tid < 81) {
        const int rr = tid / 27, o = tid - rr * 27;
        const float v = red[rr * 2 + 0][o] + red[rr * 2 + 1][o];
        const int tile = zt * 8 + yt;
        partial[(((size_t)(b * 3 + rr) * NTI + tile) * 2 + chh) * 27 + o] = v;
    }
}

// ---------------------------------------------------------------------------
// Kernel 2: reduce partials -> heat, per-batch MLP, loss + matrices + params.
// ---------------------------------------------------------------------------
__global__ __launch_bounds__(256) void k_mlp(const float* __restrict__ partial,
                                             const float* __restrict__ camg,
                                             const float* __restrict__ W1,
                                             const float* __restrict__ b1,
                                             const float* __restrict__ W2,
                                             const float* __restrict__ b2,
                                             const float* __restrict__ W3,
                                             const float* __restrict__ b3,
                                             float* __restrict__ out,
                                             float* __restrict__ params)
{
    __shared__ float heat[324];
    __shared__ float f[81];
    __shared__ float h1[128];
    __shared__ float h2[128];
    __shared__ float denom_s;
    __shared__ float res[NB][8];
    const int tid = (int)threadIdx.x;

    for (int p = tid; p < 324; p += 256) {
        const int n = p / 27, o = p % 27;
        const float* pp = partial + (size_t)n * NTI * 2 * 27 + o;
        float s = 0.0f;
        for (int t = 0; t < NTI * 2; ++t) s += pp[t * 27];
        heat[p] = s * INVC;
    }
    __syncthreads();

    for (int b = 0; b < NB; ++b) {
        if (tid < 81) {
            float v = heat[b * 81 + tid];
            f[tid] = (v >= 0.0f) ? v : 0.1f * v;
        }
        __syncthreads();
        if (tid == 0) {
            float ss = 0.0f;
            for (int k = 0; k < 81; ++k) ss += f[k] * f[k];
            denom_s = 1e-6f + sqrtf(ss);
        }
        __syncthreads();
        if (tid < 81) f[tid] = f[tid] / denom_s;
        __syncthreads();
        if (tid < 128) {
            float a = b1[tid];
            const float* wr = W1 + tid * 81;
            for (int k = 0; k < 81; ++k) a += wr[k] * f[k];
            h1[tid] = (a >= 0.0f) ? a : 0.1f * a;
        }
        __syncthreads();
        if (tid < 128) {
            float a = b2[tid];
            const float* wr = W2 + tid * 128;
            for (int k = 0; k < 128; ++k) a += wr[k] * h1[k];
            h2[tid] = (a >= 0.0f) ? a : 0.1f * a;
        }
        __syncthreads();
        if (tid < 4) {
            float a = b3[tid];
            const float* wr = W3 + tid * 128;
            for (int k = 0; k < 128; ++k) a += wr[k] * h2[k];
            res[b][4 + tid] = a;
        }
        __syncthreads();
        if (tid == 0) {
            const float r_out = res[b][4], yv = res[b][5], xv = res[b][6], zv = res[b][7];
            const float t2 = r_out * D2R;
            const float c2 = cosf(t2), s2 = sinf(t2);
            float* m = out + 1 + b * 16;
            m[0] = c2;  m[1] = 0.0f; m[2] = s2;  m[3] = -xv;
            m[4] = 0.0f; m[5] = 1.0f; m[6] = 0.0f; m[7] = -yv;
            m[8] = -s2; m[9] = 0.0f; m[10] = c2; m[11] = -zv;
            m[12] = 0.0f; m[13] = 0.0f; m[14] = 0.0f; m[15] = 1.0f;
            params[b * 8 + 0] = c2;
            params[b * 8 + 1] = s2;
            params[b * 8 + 2] = c2 * xv - s2 * zv;
            params[b * 8 + 3] = yv;
            params[b * 8 + 4] = s2 * xv + c2 * zv;
            res[b][0] = -xv; res[b][1] = -yv; res[b][2] = -zv;
            res[b][3] = atan2f(s2, c2) * R2D;
        }
        __syncthreads();
    }

    if (tid == 0) {
        float tl2 = 0.0f, dl2 = 0.0f;
        for (int b = 0; b < NB; ++b) {
            const float* g = camg + b * 16;
            const float dx = res[b][0] - g[3];
            const float dy = res[b][1] - g[7];
            const float dz = res[b][2] - g[11];
            tl2 += dx * dx + dy * dy + dz * dz;
            const float dg = atan2f(g[2], g[10]) * R2D;
            const float dd = res[b][3] - dg;
            dl2 += dd * dd;
        }
        out[0] = tl2 * 0.25f + dl2 * 0.25f;
    }
}

// ---------------------------------------------------------------------------
// Kernel 3: warp feat1 by estimated transform -> feat1_warped (d_out + 65).
// ---------------------------------------------------------------------------
__global__ __launch_bounds__(256) void k_warp(const float* __restrict__ feat1,
                                              const float* __restrict__ params,
                                              float* __restrict__ outw)
{
    const int b = blockIdx.y;
    const int p = (int)blockIdx.x * 256 + (int)threadIdx.x;
    const int z = p >> 11;
    const int y = (p >> 6) & 31;
    const int x = p & 63;

    const float cs = params[b * 8 + 0], sn = params[b * 8 + 1];
    const float tpx = params[b * 8 + 2], tpy = params[b * 8 + 3], tpz = params[b * 8 + 4];

    const float rx = (float)x - 31.5f;
    const float ry = (float)y - 15.5f;
    const float rz = (float)z - 31.5f;
    const float sx = cs * rx - sn * rz + tpx + 31.5f;
    const float sy = ry + tpy + 15.5f;
    const float sz = sn * rx + cs * rz + tpz + 31.5f;

    const float xf = floorf(sx), yf = floorf(sy), zf = floorf(sz);
    const float fx = sx - xf, fy = sy - yf, fz = sz - zf;
    const int ix = (int)xf, iy = (int)yf, iz = (int)zf;

    const float wx[2] = {1.0f - fx, fx};
    const float wy[2] = {1.0f - fy, fy};
    const float wz[2] = {1.0f - fz, fz};
    const int xs[2] = {min(max(ix, 0), 63), min(max(ix + 1, 0), 63)};
    const int ys[2] = {min(max(iy, 0), 31), min(max(iy + 1, 0), 31)};
    const int zs[2] = {min(max(iz, 0), 63), min(max(iz + 1, 0), 63)};
    const bool vx[2] = {(unsigned)ix < 64u, (unsigned)(ix + 1) < 64u};
    const bool vy[2] = {(unsigned)iy < 32u, (unsigned)(iy + 1) < 32u};
    const bool vz[2] = {(unsigned)iz < 64u, (unsigned)(iz + 1) < 64u};

    int idx[8]; float w[8];
    int q = 0;
    #pragma unroll
    for (int dz = 0; dz < 2; ++dz)
        #pragma unroll
        for (int dy = 0; dy < 2; ++dy)
            #pragma unroll
            for (int dx = 0; dx < 2; ++dx) {
                idx[q] = zs[dz] * 2048 + ys[dy] * 64 + xs[dx];
                w[q] = (vx[dx] && vy[dy] && vz[dz]) ? wx[dx] * wy[dy] * wz[dz] : 0.0f;
                ++q;
            }

    const float* f1b = feat1 + (size_t)b * NCH * CHV;
    float* ob = outw + (size_t)b * NCH * CHV;
    #pragma unroll 1
    for (int c = 0; c < NCH; ++c) {
        const float* f1c = f1b + (size_t)c * CHV;
        float a = 0.0f;
        #pragma unroll
        for (int k = 0; k < 8; ++k) a += w[k] * f1c[idx[k]];
        ob[(size_t)c * CHV + p] = a;
    }
}

// ---------------------------------------------------------------------------
extern "C" void kernel_launch(void* const* d_in, const int* in_sizes, int n_in,
                              void* d_out, int out_size, void* d_ws, size_t ws_size,
                              hipStream_t stream)
{
    (void)in_sizes; (void)n_in; (void)out_size; (void)ws_size;
    const float* feat0 = (const float*)d_in[0];
    const float* feat1 = (const float*)d_in[1];
    const float* camg  = (const float*)d_in[2];
    const float* W1 = (const float*)d_in[3];
    const float* b1 = (const float*)d_in[4];
    const float* W2 = (const float*)d_in[5];
    const float* b2 = (const float*)d_in[6];
    const float* W3 = (const float*)d_in[7];
    const float* b3 = (const float*)d_in[8];
    float* out = (float*)d_out;

    float* partial = (float*)d_ws;                 // 12*128*2*27 floats ~ 332 KB
    float* params  = partial + 12 * NTI * 2 * 27;  // 32 floats

    hipLaunchKernelGGL(k_heat, dim3(1024), dim3(384), 0, stream,
                       feat0, feat1, partial);
    hipLaunchKernelGGL(k_mlp, dim3(1), dim3(256), 0, stream,
                       partial, camg, W1, b1, W2, b2, W3, b3, out, params);
    dim3 g3((64*32*64) / 256, NB);
    hipLaunchKernelGGL(k_warp, g3, dim3(256), 0, stream, feat1, params, out + 65);
}

// Round 6
// 652.605 us; speedup vs baseline: 1.1877x; 1.1877x over previous
//
#include <hip/hip_runtime.h>
#include <math.h>

#define NCH 32
#define CHV (64*32*64)      // one channel volume
#define NB 4
#define NTI 128             // tiles per n: 16 z-tiles x 8 y-tiles
#define INVC (1.0f/(32.0f+1e-6f))
#define D2R 0.017453292519943295f
#define R2D 57.29577951308232f

// LDS slab geometry (pitch 68: +4 zeroed pad cols -> free x-edges)
#define P0 68
#define F0SZ 2448           // 6z * 6y * 68   (612 float4 chunks)
#define F1SZ 2720           // 10z * 4y * 68  (680 chunks)
#define F0B 4               // L[0..3] zero guard
#define F1B (4 + F0SZ)      // 2452, 16B-aligned
#define BUFSZ (4 + F0SZ + F1SZ)   // 5172 floats per buffer (20.7 KB)
#define NCK 1292            // total float4 chunks per channel

// ---------------------------------------------------------------------------
// Kernel 1: fused rotate-warp(feat1) x 27-offset correlation vs feat0.
// Block = (b, 4z x 4y x 64x tile, channel-half): 384 threads (6 waves),
// waves {0,1}->rot0, {2,3}->rot1(identity), {4,5}->rot2. Thread owns 2z x 4x.
// 3 blocks/CU co-resident; double-buffered LDS; edges via shuffles.
// NOTE launch_bounds(384,4): VGPR cap 128 (needs ~84). (384,5) capped at
// ~102 and the allocator spilled acc[27] to scratch -> 2.5 GB HBM traffic.
// ---------------------------------------------------------------------------
__global__ __launch_bounds__(384, 4) void k_heat(const float* __restrict__ feat0,
                                                 const float* __restrict__ feat1,
                                                 float* __restrict__ partial)
{
    __shared__ float L[2][BUFSZ];
    __shared__ float red[6][27];

    // XCD-chunked remap: each XCD gets 128 consecutive nids (same b, z-adjacent)
    const int lid = (int)blockIdx.x;               // 0..1023
    const int nid = (lid & 7) * 128 + (lid >> 3);
    const int b   = nid >> 8;
    const int rr_ = nid & 255;
    const int zt  = rr_ >> 4;                      // 0..15
    const int yt  = (rr_ >> 1) & 7;                // 0..7
    const int chh = rr_ & 1;                       // channel half

    const int tid = (int)threadIdx.x;
    const int wv = tid >> 6;            // 0..5
    const int lane = tid & 63;
    const int rot = wv >> 1;            // 0,1,2
    const int ww = wv & 1;              // z-pair within rotation group
    const int tx = lane & 15, ty = lane >> 4;
    const int z0 = 4 * zt + 2 * ww;     // owns z0, z0+1
    const int x0 = 4 * tx;

    if (tid < 8) L[tid >> 2][tid & 3] = 0.0f;   // zero guards

    const float th = 4.0f * (float)(rot - 1) * D2R;
    const float cs = cosf(th), sn = sinf(th);

    // ---- bilinear setup (channel-invariant); rot==1 never uses it ----
    float WX0[2][4], WX1[2][4], WZ0[2][4];
    int A1[2][4];
    #pragma unroll
    for (int j = 0; j < 2; ++j) {
        #pragma unroll
        for (int i = 0; i < 4; ++i) {
            const float rx = (float)(x0 + i) - 31.5f;
            const float rz = (float)(z0 + j) - 31.5f;
            const float sx = cs * rx - sn * rz + 31.5f;
            const float sz = sn * rx + cs * rz + 31.5f;
            const float xf = floorf(sx), zf = floorf(sz);
            const float fx = sx - xf, fz = sz - zf;
            const int ix = (int)xf, iz = (int)zf;
            WX0[j][i] = ((unsigned)ix < 64u) ? (1.0f - fx) : 0.0f;
            WX1[j][i] = ((unsigned)(ix + 1) < 64u) ? fx : 0.0f;
            WZ0[j][i] = 1.0f - fz;      // z-OOB rows staged as zeros
            int zl = iz - (4 * zt - 3);
            zl = min(max(zl, 0), 8);
            const int bx = min(max(ix, -1), 63);
            A1[j][i] = F1B + (zl * 4 + ty) * P0 + bx;
        }
    }
    const int A1r1 = F1B + ((2 * ww + 3) * 4 + ty) * P0 + x0;   // identity rows

    // ---- staging map: 1292 chunks, thread t takes f = t + 384k ----
    const float* f0b_ = feat0 + ((size_t)b * NCH + 16 * chh) * CHV;
    const float* f1b_ = feat1 + ((size_t)b * NCH + 16 * chh) * CHV;
    const float* gp[4];
    float gmask[4];
    int wof[4];
    const int nld = (tid < 140) ? 4 : 3;
    #pragma unroll
    for (int k = 0; k < 4; ++k) {
        const int f = tid + 384 * k;
        wof[k] = 4 + 4 * f;
        gmask[k] = 0.0f;
        gp[k] = f0b_;
        if (f < NCK) {
            if (f < 612) {              // feat0 slab [6][6][68], z/y halo -1
                const int q = 4 * f;
                const int zr = q / 408; const int rem = q - zr * 408;
                const int yr = rem / 68; const int x = rem - yr * 68;
                const int zs = 4 * zt - 1 + zr, ys = 4 * yt - 1 + yr;
                const int ok = (x < 64) & (zs >= 0) & (zs < 64)
                             & (ys >= 0) & (ys < 32);
                gp[k] = f0b_ + (ok ? (zs * 2048 + ys * 64 + x) : 0);
                gmask[k] = ok ? 1.0f : 0.0f;
            } else {                    // feat1 slab [10][4][68], z halo -3
                const int q = 4 * f - F0SZ;
                const int zr = q / 272; const int rem = q - zr * 272;
                const int yr = rem / 68; const int x = rem - yr * 68;
                const int zs = 4 * zt - 3 + zr, ys = 4 * yt + yr;
                const int ok = (x < 64) & (zs >= 0) & (zs < 64);
                gp[k] = f1b_ + (ok ? (zs * 2048 + ys * 64 + x) : 0);
                gmask[k] = ok ? 1.0f : 0.0f;
            }
        }
    }

    const int rw = F0B + (2 * ww * 6 + ty) * P0 + x0;   // feat0 corr row base

    float acc[27];
    #pragma unroll
    for (int o = 0; o < 27; ++o) acc[o] = 0.0f;

    // ---- prologue: stage first channel into buffer 0 ----
    {
        float4 vv[4];
        #pragma unroll
        for (int k = 0; k < 4; ++k) if (k < nld) vv[k] = *(const float4*)gp[k];
        #pragma unroll
        for (int k = 0; k < 4; ++k) gp[k] += CHV;
        #pragma unroll
        for (int k = 0; k < 4; ++k) if (k < nld) {
            float4 v = vv[k]; const float m = gmask[k];
            v.x *= m; v.y *= m; v.z *= m; v.w *= m;
            *(float4*)&L[0][wof[k]] = v;
        }
    }
    __syncthreads();

    #pragma unroll 1
    for (int ch = 0; ch < 16; ++ch) {
        const float* Lb = &L[ch & 1][0];

        // issue next channel's loads first (latency hides under compute)
        float4 nv[4];
        if (ch + 1 < 16) {
            #pragma unroll
            for (int k = 0; k < 4; ++k) if (k < nld) nv[k] = *(const float4*)gp[k];
            #pragma unroll
            for (int k = 0; k < 4; ++k) gp[k] += CHV;
        }

        // ---- warp-sample 8 positions ----
        float fa[4], fb[4];
        if (rot == 1) {                 // identity: direct aligned rows
            const float4 a4 = *(const float4*)&Lb[A1r1];
            const float4 b4 = *(const float4*)&Lb[A1r1 + 4 * P0];
            fa[0] = a4.x; fa[1] = a4.y; fa[2] = a4.z; fa[3] = a4.w;
            fb[0] = b4.x; fb[1] = b4.y; fb[2] = b4.z; fb[3] = b4.w;
        } else {
            #pragma unroll
            for (int j = 0; j < 2; ++j) {
                #pragma unroll
                for (int i = 0; i < 4; ++i) {
                    const int a = A1[j][i];
                    const float p00 = Lb[a], p01 = Lb[a + 1];
                    const float p10 = Lb[a + 4 * P0], p11 = Lb[a + 4 * P0 + 1];
                    const float w0 = WZ0[j][i];
                    const float t = w0 * p00 + (1.0f - w0) * p10;
                    const float u = w0 * p01 + (1.0f - w0) * p11;
                    const float v_ = WX0[j][i] * t + WX1[j][i] * u;
                    if (j == 0) fa[i] = v_; else fb[i] = v_;
                }
            }
        }

        // ---- correlation: 12 feat0 rows; x-edges via wave shuffles ----
        #pragma unroll
        for (int yri = 0; yri < 3; ++yri) {
            #pragma unroll
            for (int zri = 0; zri < 4; ++zri) {
                const int off = zri * 408 + yri * 68;
                const float4 m4 = *(const float4*)&Lb[rw + off];
                const float e0s = __shfl_up(m4.w, 1, 64);
                const float e1s = __shfl_down(m4.x, 1, 64);
                const float e0 = (tx == 0) ? 0.0f : e0s;
                const float e1 = (tx == 15) ? 0.0f : e1s;
                const int oy1 = 2 - yri;
                if (zri <= 2) {         // owned z0: oz+1 = 2-zri
                    const int ob = (2 - zri) * 9 + oy1 * 3;
                    acc[ob + 0] += fa[0] * m4.y + fa[1] * m4.z + fa[2] * m4.w + fa[3] * e1;
                    acc[ob + 1] += fa[0] * m4.x + fa[1] * m4.y + fa[2] * m4.z + fa[3] * m4.w;
                    acc[ob + 2] += fa[0] * e0   + fa[1] * m4.x + fa[2] * m4.y + fa[3] * m4.z;
                }
                if (zri >= 1) {         // owned z0+1: oz+1 = 3-zri
                    const int ob = (3 - zri) * 9 + oy1 * 3;
                    acc[ob + 0] += fb[0] * m4.y + fb[1] * m4.z + fb[2] * m4.w + fb[3] * e1;
                    acc[ob + 1] += fb[0] * m4.x + fb[1] * m4.y + fb[2] * m4.z + fb[3] * m4.w;
                    acc[ob + 2] += fb[0] * e0   + fb[1] * m4.x + fb[2] * m4.y + fb[3] * m4.z;
                }
            }
        }

        // ---- write next channel into the other buffer ----
        if (ch + 1 < 16) {
            float* Ln = &L[(ch + 1) & 1][0];
            #pragma unroll
            for (int k = 0; k < 4; ++k) if (k < nld) {
                float4 v = nv[k]; const float m = gmask[k];
                v.x *= m; v.y *= m; v.z *= m; v.w *= m;
                *(float4*)&Ln[wof[k]] = v;
            }
        }
        __syncthreads();
    }

    // ---- reduction (fixed order -> deterministic) ----
    #pragma unroll 1
    for (int o = 0; o < 27; ++o) {
        float v = acc[o];
        #pragma unroll
        for (int d = 32; d >= 1; d >>= 1) v += __shfl_down(v, d, 64);
        if (lane == 0) red[wv][o] = v;
    }
    __syncthreads();
    if (tid < 81) {
        const int rr = tid / 27, o = tid - rr * 27;
        const float v = red[rr * 2 + 0][o] + red[rr * 2 + 1][o];
        const int tile = zt * 8 + yt;
        partial[(((size_t)(b * 3 + rr) * NTI + tile) * 2 + chh) * 27 + o] = v;
    }
}

// ---------------------------------------------------------------------------
// Kernel 2: reduce partials -> heat, per-batch MLP, loss + matrices + params.
// ---------------------------------------------------------------------------
__global__ __launch_bounds__(256) void k_mlp(const float* __restrict__ partial,
                                             const float* __restrict__ camg,
                                             const float* __restrict__ W1,
                                             const float* __restrict__ b1,
                                             const float* __restrict__ W2,
                                             const float* __restrict__ b2,
                                             const float* __restrict__ W3,
                                             const float* __restrict__ b3,
                                             float* __restrict__ out,
                                             float* __restrict__ params)
{
    __shared__ float heat[324];
    __shared__ float f[81];
    __shared__ float h1[128];
    __shared__ float h2[128];
    __shared__ float denom_s;
    __shared__ float res[NB][8];
    const int tid = (int)threadIdx.x;

    for (int p = tid; p < 324; p += 256) {
        const int n = p / 27, o = p % 27;
        const float* pp = partial + (size_t)n * NTI * 2 * 27 + o;
        float s = 0.0f;
        for (int t = 0; t < NTI * 2; ++t) s += pp[t * 27];
        heat[p] = s * INVC;
    }
    __syncthreads();

    for (int b = 0; b < NB; ++b) {
        if (tid < 81) {
            float v = heat[b * 81 + tid];
            f[tid] = (v >= 0.0f) ? v : 0.1f * v;
        }
        __syncthreads();
        if (tid == 0) {
            float ss = 0.0f;
            for (int k = 0; k < 81; ++k) ss += f[k] * f[k];
            denom_s = 1e-6f + sqrtf(ss);
        }
        __syncthreads();
        if (tid < 81) f[tid] = f[tid] / denom_s;
        __syncthreads();
        if (tid < 128) {
            float a = b1[tid];
            const float* wr = W1 + tid * 81;
            for (int k = 0; k < 81; ++k) a += wr[k] * f[k];
            h1[tid] = (a >= 0.0f) ? a : 0.1f * a;
        }
        __syncthreads();
        if (tid < 128) {
            float a = b2[tid];
            const float* wr = W2 + tid * 128;
            for (int k = 0; k < 128; ++k) a += wr[k] * h1[k];
            h2[tid] = (a >= 0.0f) ? a : 0.1f * a;
        }
        __syncthreads();
        if (tid < 4) {
            float a = b3[tid];
            const float* wr = W3 + tid * 128;
            for (int k = 0; k < 128; ++k) a += wr[k] * h2[k];
            res[b][4 + tid] = a;
        }
        __syncthreads();
        if (tid == 0) {
            const float r_out = res[b][4], yv = res[b][5], xv = res[b][6], zv = res[b][7];
            const float t2 = r_out * D2R;
            const float c2 = cosf(t2), s2 = sinf(t2);
            float* m = out + 1 + b * 16;
            m[0] = c2;  m[1] = 0.0f; m[2] = s2;  m[3] = -xv;
            m[4] = 0.0f; m[5] = 1.0f; m[6] = 0.0f; m[7] = -yv;
            m[8] = -s2; m[9] = 0.0f; m[10] = c2; m[11] = -zv;
            m[12] = 0.0f; m[13] = 0.0f; m[14] = 0.0f; m[15] = 1.0f;
            params[b * 8 + 0] = c2;
            params[b * 8 + 1] = s2;
            params[b * 8 + 2] = c2 * xv - s2 * zv;
            params[b * 8 + 3] = yv;
            params[b * 8 + 4] = s2 * xv + c2 * zv;
            res[b][0] = -xv; res[b][1] = -yv; res[b][2] = -zv;
            res[b][3] = atan2f(s2, c2) * R2D;
        }
        __syncthreads();
    }

    if (tid == 0) {
        float tl2 = 0.0f, dl2 = 0.0f;
        for (int b = 0; b < NB; ++b) {
            const float* g = camg + b * 16;
            const float dx = res[b][0] - g[3];
            const float dy = res[b][1] - g[7];
            const float dz = res[b][2] - g[11];
            tl2 += dx * dx + dy * dy + dz * dz;
            const float dg = atan2f(g[2], g[10]) * R2D;
            const float dd = res[b][3] - dg;
            dl2 += dd * dd;
        }
        out[0] = tl2 * 0.25f + dl2 * 0.25f;
    }
}

// ---------------------------------------------------------------------------
// Kernel 3: warp feat1 by estimated transform -> feat1_warped (d_out + 65).
// ---------------------------------------------------------------------------
__global__ __launch_bounds__(256) void k_warp(const float* __restrict__ feat1,
                                              const float* __restrict__ params,
                                              float* __restrict__ outw)
{
    const int b = blockIdx.y;
    const int p = (int)blockIdx.x * 256 + (int)threadIdx.x;
    const int z = p >> 11;
    const int y = (p >> 6) & 31;
    const int x = p & 63;

    const float cs = params[b * 8 + 0], sn = params[b * 8 + 1];
    const float tpx = params[b * 8 + 2], tpy = params[b * 8 + 3], tpz = params[b * 8 + 4];

    const float rx = (float)x - 31.5f;
    const float ry = (float)y - 15.5f;
    const float rz = (float)z - 31.5f;
    const float sx = cs * rx - sn * rz + tpx + 31.5f;
    const float sy = ry + tpy + 15.5f;
    const float sz = sn * rx + cs * rz + tpz + 31.5f;

    const float xf = floorf(sx), yf = floorf(sy), zf = floorf(sz);
    const float fx = sx - xf, fy = sy - yf, fz = sz - zf;
    const int ix = (int)xf, iy = (int)yf, iz = (int)zf;

    const float wx[2] = {1.0f - fx, fx};
    const float wy[2] = {1.0f - fy, fy};
    const float wz[2] = {1.0f - fz, fz};
    const int xs[2] = {min(max(ix, 0), 63), min(max(ix + 1, 0), 63)};
    const int ys[2] = {min(max(iy, 0), 31), min(max(iy + 1, 0), 31)};
    const int zs[2] = {min(max(iz, 0), 63), min(max(iz + 1, 0), 63)};
    const bool vx[2] = {(unsigned)ix < 64u, (unsigned)(ix + 1) < 64u};
    const bool vy[2] = {(unsigned)iy < 32u, (unsigned)(iy + 1) < 32u};
    const bool vz[2] = {(unsigned)iz < 64u, (unsigned)(iz + 1) < 64u};

    int idx[8]; float w[8];
    int q = 0;
    #pragma unroll
    for (int dz = 0; dz < 2; ++dz)
        #pragma unroll
        for (int dy = 0; dy < 2; ++dy)
            #pragma unroll
            for (int dx = 0; dx < 2; ++dx) {
                idx[q] = zs[dz] * 2048 + ys[dy] * 64 + xs[dx];
                w[q] = (vx[dx] && vy[dy] && vz[dz]) ? wx[dx] * wy[dy] * wz[dz] : 0.0f;
                ++q;
            }

    const float* f1b = feat1 + (size_t)b * NCH * CHV;
    float* ob = outw + (size_t)b * NCH * CHV;
    #pragma unroll 1
    for (int c = 0; c < NCH; ++c) {
        const float* f1c = f1b + (size_t)c * CHV;
        float a = 0.0f;
        #pragma unroll
        for (int k = 0; k < 8; ++k) a += w[k] * f1c[idx[k]];
        ob[(size_t)c * CHV + p] = a;
    }
}

// ---------------------------------------------------------------------------
extern "C" void kernel_launch(void* const* d_in, const int* in_sizes, int n_in,
                              void* d_out, int out_size, void* d_ws, size_t ws_size,
                              hipStream_t stream)
{
    (void)in_sizes; (void)n_in; (void)out_size; (void)ws_size;
    const float* feat0 = (const float*)d_in[0];
    const float* feat1 = (const float*)d_in[1];
    const float* camg  = (const float*)d_in[2];
    const float* W1 = (const float*)d_in[3];
    const float* b1 = (const float*)d_in[4];
    const float* W2 = (const float*)d_in[5];
    const float* b2 = (const float*)d_in[6];
    const float* W3 = (const float*)d_in[7];
    const float* b3 = (const float*)d_in[8];
    float* out = (float*)d_out;

    float* partial = (float*)d_ws;                 // 12*128*2*27 floats ~ 332 KB
    float* params  = partial + 12 * NTI * 2 * 27;  // 32 floats

    hipLaunchKernelGGL(k_heat, dim3(1024), dim3(384), 0, stream,
                       feat0, feat1, partial);
    hipLaunchKernelGGL(k_mlp, dim3(1), dim3(256), 0, stream,
                       partial, camg, W1, b1, W2, b2, W3, b3, out, params);
    dim3 g3((64*32*64) / 256, NB);
    hipLaunchKernelGGL(k_warp, g3, dim3(256), 0, stream, feat1, params, out + 65);
}

// Round 7
// 263.229 us; speedup vs baseline: 2.9445x; 2.4792x over previous
//
#include <hip/hip_runtime.h>
#include <math.h>

#define NCH 32
#define CHV (64*32*64)      // one channel volume
#define NB 4
#define NTI 128             // tiles per n: 16 z-tiles x 8 y-tiles
#define INVC (1.0f/(32.0f+1e-6f))
#define D2R 0.017453292519943295f
#define R2D 57.29577951308232f

// LDS slab geometry.
// feat0 slab: pitch 68 (16B-aligned b128 row reads; banks 2-way across wave).
// feat1 slab: pitch 69 (odd mod 32 -> scalar bilinear reads spread over all
// 32 banks ~2-way instead of the multiple-of-4 lattice's 8-way).
#define P0 68
#define P1 69
#define F0SZ 2448           // 6z * 6y * 68  (612 float4 chunks)
#define F1SRC 2720          // source flat size 10z*4y*68 (680 chunks)
#define F1SZ 2760           // dst 10z*4y rows * 69
#define F0B 4               // L[0..3] zero guard
#define F1B (4 + F0SZ)      // 2452
#define BUFSZ (4 + F0SZ + F1SZ)   // 5212 floats (20.8 KB) per buffer
#define NCK 1292            // total float4 chunks per channel (612 + 680)

// ---------------------------------------------------------------------------
// Kernel 1: fused rotate-warp(feat1) x 27-offset correlation vs feat0.
// Block = (b, 4z x 4y x 64x tile, channel-half): 384 threads (6 waves),
// waves {0,1}->rot0, {2,3}->rot1(identity), {4,5}->rot2. Thread owns 2z x 4x.
// NOTE: no min-occupancy launch bound. (384,5) and (384,4) both forced the
// allocator to a spilling register budget (VGPR 48/64, 0.5-2.5 GB scratch
// traffic). Unconstrained it needs ~90 VGPR -> 3 blocks/CU via LDS limit.
// ---------------------------------------------------------------------------
__global__ __launch_bounds__(384) void k_heat(const float* __restrict__ feat0,
                                              const float* __restrict__ feat1,
                                              float* __restrict__ partial)
{
    __shared__ float L[2][BUFSZ];
    __shared__ float red[6][27];

    // XCD-chunked remap: each XCD gets 128 consecutive nids (same b, z-adjacent)
    const int lid = (int)blockIdx.x;               // 0..1023
    const int nid = (lid & 7) * 128 + (lid >> 3);
    const int b   = nid >> 8;
    const int rr_ = nid & 255;
    const int zt  = rr_ >> 4;                      // 0..15
    const int yt  = (rr_ >> 1) & 7;                // 0..7
    const int chh = rr_ & 1;                       // channel half

    const int tid = (int)threadIdx.x;
    const int wv = tid >> 6;            // 0..5
    const int lane = tid & 63;
    const int rot = wv >> 1;            // 0,1,2
    const int ww = wv & 1;              // z-pair within rotation group
    const int tx = lane & 15, ty = lane >> 4;
    const int z0 = 4 * zt + 2 * ww;     // owns z0, z0+1
    const int x0 = 4 * tx;

    // zero guards: feat0 e0 guard + feat1 col-68 (never written by staging,
    // read only as the weight-0 bx=-1 corner -> must be finite zero).
    if (tid < 8) L[tid >> 2][tid & 3] = 0.0f;
    for (int i = tid; i < 80; i += 384) {
        const int bufi = i / 40, r = i - 40 * bufi;
        L[bufi][F1B + r * P1 + 68] = 0.0f;
    }

    const float th = 4.0f * (float)(rot - 1) * D2R;
    const float cs = cosf(th), sn = sinf(th);

    // ---- bilinear setup (channel-invariant); rot==1 never uses it ----
    float WX0[2][4], WX1[2][4], WZ0[2][4];
    int A1[2][4];
    #pragma unroll
    for (int j = 0; j < 2; ++j) {
        #pragma unroll
        for (int i = 0; i < 4; ++i) {
            const float rx = (float)(x0 + i) - 31.5f;
            const float rz = (float)(z0 + j) - 31.5f;
            const float sx = cs * rx - sn * rz + 31.5f;
            const float sz = sn * rx + cs * rz + 31.5f;
            const float xf = floorf(sx), zf = floorf(sz);
            const float fx = sx - xf, fz = sz - zf;
            const int ix = (int)xf, iz = (int)zf;
            WX0[j][i] = ((unsigned)ix < 64u) ? (1.0f - fx) : 0.0f;
            WX1[j][i] = ((unsigned)(ix + 1) < 64u) ? fx : 0.0f;
            WZ0[j][i] = 1.0f - fz;      // z-OOB rows staged as zeros
            int zl = iz - (4 * zt - 3);
            zl = min(max(zl, 0), 8);
            const int bx = min(max(ix, -1), 63);
            A1[j][i] = F1B + (zl * 4 + ty) * P1 + bx;
        }
    }
    const int A1r1 = F1B + ((2 * ww + 3) * 4 + ty) * P1 + x0;   // identity rows

    // ---- staging map: 1292 chunks, thread t takes f = t + 384k.
    // Source mapping stays pitch-68 flat (float4, no row straddle); feat1
    // chunks write to the pitch-69 slab via 4x b32.
    const float* f0b_ = feat0 + ((size_t)b * NCH + 16 * chh) * CHV;
    const float* f1b_ = feat1 + ((size_t)b * NCH + 16 * chh) * CHV;
    const float* gp[4];
    float gmask[4];
    int wof[4];
    int isf0[4];
    const int nld = (tid < 140) ? 4 : 3;
    #pragma unroll
    for (int k = 0; k < 4; ++k) {
        const int f = tid + 384 * k;
        gmask[k] = 0.0f;
        gp[k] = f0b_;
        wof[k] = 4;
        isf0[k] = 1;
        if (f < NCK) {
            if (f < 612) {              // feat0 slab [6][6][68], z/y halo -1
                const int q = 4 * f;
                const int zr = q / 408; const int rem = q - zr * 408;
                const int yr = rem / 68; const int x = rem - yr * 68;
                const int zs = 4 * zt - 1 + zr, ys = 4 * yt - 1 + yr;
                const int ok = (x < 64) & (zs >= 0) & (zs < 64)
                             & (ys >= 0) & (ys < 32);
                gp[k] = f0b_ + (ok ? (zs * 2048 + ys * 64 + x) : 0);
                gmask[k] = ok ? 1.0f : 0.0f;
                wof[k] = 4 + q;         // linear dst
            } else {                    // feat1 slab [10][4] rows, dst pitch 69
                const int q = 4 * f - F0SZ;        // 0..2716, mult of 4
                const int zr = q / 272; const int rem = q - zr * 272;
                const int yr = rem / 68; const int x = rem - yr * 68;
                const int zs = 4 * zt - 3 + zr, ys = 4 * yt + yr;
                const int ok = (x < 64) & (zs >= 0) & (zs < 64);
                gp[k] = f1b_ + (ok ? (zs * 2048 + ys * 64 + x) : 0);
                gmask[k] = ok ? 1.0f : 0.0f;
                wof[k] = F1B + (zr * 4 + yr) * P1 + x;
                isf0[k] = 0;
            }
        }
    }

    const int rw = F0B + (2 * ww * 6 + ty) * P0 + x0;   // feat0 corr row base

    float acc[27];
    #pragma unroll
    for (int o = 0; o < 27; ++o) acc[o] = 0.0f;

    // ---- prologue: stage first channel into buffer 0 ----
    {
        float4 vv[4];
        #pragma unroll
        for (int k = 0; k < 4; ++k) if (k < nld) vv[k] = *(const float4*)gp[k];
        #pragma unroll
        for (int k = 0; k < 4; ++k) gp[k] += CHV;
        #pragma unroll
        for (int k = 0; k < 4; ++k) if (k < nld) {
            float4 v = vv[k]; const float m = gmask[k];
            v.x *= m; v.y *= m; v.z *= m; v.w *= m;
            if (isf0[k]) { *(float4*)&L[0][wof[k]] = v; }
            else {
                L[0][wof[k] + 0] = v.x; L[0][wof[k] + 1] = v.y;
                L[0][wof[k] + 2] = v.z; L[0][wof[k] + 3] = v.w;
            }
        }
    }
    __syncthreads();

    #pragma unroll 1
    for (int ch = 0; ch < 16; ++ch) {
        const float* Lb = &L[ch & 1][0];

        // issue next channel's loads first (latency hides under compute)
        float4 nv[4];
        if (ch + 1 < 16) {
            #pragma unroll
            for (int k = 0; k < 4; ++k) if (k < nld) nv[k] = *(const float4*)gp[k];
            #pragma unroll
            for (int k = 0; k < 4; ++k) gp[k] += CHV;
        }

        // ---- warp-sample 8 positions ----
        float fa[4], fb[4];
        if (rot == 1) {                 // identity: scalar rows (2-way banks)
            #pragma unroll
            for (int i = 0; i < 4; ++i) {
                fa[i] = Lb[A1r1 + i];
                fb[i] = Lb[A1r1 + 4 * P1 + i];
            }
        } else {
            #pragma unroll
            for (int j = 0; j < 2; ++j) {
                #pragma unroll
                for (int i = 0; i < 4; ++i) {
                    const int a = A1[j][i];
                    const float p00 = Lb[a], p01 = Lb[a + 1];
                    const float p10 = Lb[a + 4 * P1], p11 = Lb[a + 4 * P1 + 1];
                    const float w0 = WZ0[j][i];
                    const float t = w0 * p00 + (1.0f - w0) * p10;
                    const float u = w0 * p01 + (1.0f - w0) * p11;
                    const float v_ = WX0[j][i] * t + WX1[j][i] * u;
                    if (j == 0) fa[i] = v_; else fb[i] = v_;
                }
            }
        }

        // ---- correlation: 12 feat0 rows; x-edges via wave shuffles ----
        #pragma unroll
        for (int yri = 0; yri < 3; ++yri) {
            #pragma unroll
            for (int zri = 0; zri < 4; ++zri) {
                const int off = zri * 408 + yri * 68;
                const float4 m4 = *(const float4*)&Lb[rw + off];
                const float e0s = __shfl_up(m4.w, 1, 64);
                const float e1s = __shfl_down(m4.x, 1, 64);
                const float e0 = (tx == 0) ? 0.0f : e0s;
                const float e1 = (tx == 15) ? 0.0f : e1s;
                const int oy1 = 2 - yri;
                if (zri <= 2) {         // owned z0: oz+1 = 2-zri
                    const int ob = (2 - zri) * 9 + oy1 * 3;
                    acc[ob + 0] += fa[0] * m4.y + fa[1] * m4.z + fa[2] * m4.w + fa[3] * e1;
                    acc[ob + 1] += fa[0] * m4.x + fa[1] * m4.y + fa[2] * m4.z + fa[3] * m4.w;
                    acc[ob + 2] += fa[0] * e0   + fa[1] * m4.x + fa[2] * m4.y + fa[3] * m4.z;
                }
                if (zri >= 1) {         // owned z0+1: oz+1 = 3-zri
                    const int ob = (3 - zri) * 9 + oy1 * 3;
                    acc[ob + 0] += fb[0] * m4.y + fb[1] * m4.z + fb[2] * m4.w + fb[3] * e1;
                    acc[ob + 1] += fb[0] * m4.x + fb[1] * m4.y + fb[2] * m4.z + fb[3] * m4.w;
                    acc[ob + 2] += fb[0] * e0   + fb[1] * m4.x + fb[2] * m4.y + fb[3] * m4.z;
                }
            }
        }

        // ---- write next channel into the other buffer ----
        if (ch + 1 < 16) {
            float* Ln = &L[(ch + 1) & 1][0];
            #pragma unroll
            for (int k = 0; k < 4; ++k) if (k < nld) {
                float4 v = nv[k]; const float m = gmask[k];
                v.x *= m; v.y *= m; v.z *= m; v.w *= m;
                if (isf0[k]) { *(float4*)&Ln[wof[k]] = v; }
                else {
                    Ln[wof[k] + 0] = v.x; Ln[wof[k] + 1] = v.y;
                    Ln[wof[k] + 2] = v.z; Ln[wof[k] + 3] = v.w;
                }
            }
        }
        __syncthreads();
    }

    // ---- reduction (fixed order -> deterministic) ----
    #pragma unroll 1
    for (int o = 0; o < 27; ++o) {
        float v = acc[o];
        #pragma unroll
        for (int d = 32; d >= 1; d >>= 1) v += __shfl_down(v, d, 64);
        if (lane == 0) red[wv][o] = v;
    }
    __syncthreads();
    if (tid < 81) {
        const int rr = tid / 27, o = tid - rr * 27;
        const float v = red[rr * 2 + 0][o] + red[rr * 2 + 1][o];
        const int tile = zt * 8 + yt;
        partial[(((size_t)(b * 3 + rr) * NTI + tile) * 2 + chh) * 27 + o] = v;
    }
}

// ---------------------------------------------------------------------------
// Kernel 2: reduce partials -> heat, per-batch MLP, loss + matrices + params.
// ---------------------------------------------------------------------------
__global__ __launch_bounds__(256) void k_mlp(const float* __restrict__ partial,
                                             const float* __restrict__ camg,
                                             const float* __restrict__ W1,
                                             const float* __restrict__ b1,
                                             const float* __restrict__ W2,
                                             const float* __restrict__ b2,
                                             const float* __restrict__ W3,
                                             const float* __restrict__ b3,
                                             float* __restrict__ out,
                                             float* __restrict__ params)
{
    __shared__ float heat[324];
    __shared__ float f[81];
    __shared__ float h1[128];
    __shared__ float h2[128];
    __shared__ float denom_s;
    __shared__ float res[NB][8];
    const int tid = (int)threadIdx.x;

    for (int p = tid; p < 324; p += 256) {
        const int n = p / 27, o = p % 27;
        const float* pp = partial + (size_t)n * NTI * 2 * 27 + o;
        float s = 0.0f;
        for (int t = 0; t < NTI * 2; ++t) s += pp[t * 27];
        heat[p] = s * INVC;
    }
    __syncthreads();

    for (int b = 0; b < NB; ++b) {
        if (tid < 81) {
            float v = heat[b * 81 + tid];
            f[tid] = (v >= 0.0f) ? v : 0.1f * v;
        }
        __syncthreads();
        if (tid == 0) {
            float ss = 0.0f;
            for (int k = 0; k < 81; ++k) ss += f[k] * f[k];
            denom_s = 1e-6f + sqrtf(ss);
        }
        __syncthreads();
        if (tid < 81) f[tid] = f[tid] / denom_s;
        __syncthreads();
        if (tid < 128) {
            float a = b1[tid];
            const float* wr = W1 + tid * 81;
            for (int k = 0; k < 81; ++k) a += wr[k] * f[k];
            h1[tid] = (a >= 0.0f) ? a : 0.1f * a;
        }
        __syncthreads();
        if (tid < 128) {
            float a = b2[tid];
            const float* wr = W2 + tid * 128;
            for (int k = 0; k < 128; ++k) a += wr[k] * h1[k];
            h2[tid] = (a >= 0.0f) ? a : 0.1f * a;
        }
        __syncthreads();
        if (tid < 4) {
            float a = b3[tid];
            const float* wr = W3 + tid * 128;
            for (int k = 0; k < 128; ++k) a += wr[k] * h2[k];
            res[b][4 + tid] = a;
        }
        __syncthreads();
        if (tid == 0) {
            const float r_out = res[b][4], yv = res[b][5], xv = res[b][6], zv = res[b][7];
            const float t2 = r_out * D2R;
            const float c2 = cosf(t2), s2 = sinf(t2);
            float* m = out + 1 + b * 16;
            m[0] = c2;  m[1] = 0.0f; m[2] = s2;  m[3] = -xv;
            m[4] = 0.0f; m[5] = 1.0f; m[6] = 0.0f; m[7] = -yv;
            m[8] = -s2; m[9] = 0.0f; m[10] = c2; m[11] = -zv;
            m[12] = 0.0f; m[13] = 0.0f; m[14] = 0.0f; m[15] = 1.0f;
            params[b * 8 + 0] = c2;
            params[b * 8 + 1] = s2;
            params[b * 8 + 2] = c2 * xv - s2 * zv;
            params[b * 8 + 3] = yv;
            params[b * 8 + 4] = s2 * xv + c2 * zv;
            res[b][0] = -xv; res[b][1] = -yv; res[b][2] = -zv;
            res[b][3] = atan2f(s2, c2) * R2D;
        }
        __syncthreads();
    }

    if (tid == 0) {
        float tl2 = 0.0f, dl2 = 0.0f;
        for (int b = 0; b < NB; ++b) {
            const float* g = camg + b * 16;
            const float dx = res[b][0] - g[3];
            const float dy = res[b][1] - g[7];
            const float dz = res[b][2] - g[11];
            tl2 += dx * dx + dy * dy + dz * dz;
            const float dg = atan2f(g[2], g[10]) * R2D;
            const float dd = res[b][3] - dg;
            dl2 += dd * dd;
        }
        out[0] = tl2 * 0.25f + dl2 * 0.25f;
    }
}

// ---------------------------------------------------------------------------
// Kernel 3: warp feat1 by estimated transform -> feat1_warped (d_out + 65).
// ---------------------------------------------------------------------------
__global__ __launch_bounds__(256) void k_warp(const float* __restrict__ feat1,
                                              const float* __restrict__ params,
                                              float* __restrict__ outw)
{
    const int b = blockIdx.y;
    const int p = (int)blockIdx.x * 256 + (int)threadIdx.x;
    const int z = p >> 11;
    const int y = (p >> 6) & 31;
    const int x = p & 63;

    const float cs = params[b * 8 + 0], sn = params[b * 8 + 1];
    const float tpx = params[b * 8 + 2], tpy = params[b * 8 + 3], tpz = params[b * 8 + 4];

    const float rx = (float)x - 31.5f;
    const float ry = (float)y - 15.5f;
    const float rz = (float)z - 31.5f;
    const float sx = cs * rx - sn * rz + tpx + 31.5f;
    const float sy = ry + tpy + 15.5f;
    const float sz = sn * rx + cs * rz + tpz + 31.5f;

    const float xf = floorf(sx), yf = floorf(sy), zf = floorf(sz);
    const float fx = sx - xf, fy = sy - yf, fz = sz - zf;
    const int ix = (int)xf, iy = (int)yf, iz = (int)zf;

    const float wx[2] = {1.0f - fx, fx};
    const float wy[2] = {1.0f - fy, fy};
    const float wz[2] = {1.0f - fz, fz};
    const int xs[2] = {min(max(ix, 0), 63), min(max(ix + 1, 0), 63)};
    const int ys[2] = {min(max(iy, 0), 31), min(max(iy + 1, 0), 31)};
    const int zs[2] = {min(max(iz, 0), 63), min(max(iz + 1, 0), 63)};
    const bool vx[2] = {(unsigned)ix < 64u, (unsigned)(ix + 1) < 64u};
    const bool vy[2] = {(unsigned)iy < 32u, (unsigned)(iy + 1) < 32u};
    const bool vz[2] = {(unsigned)iz < 64u, (unsigned)(iz + 1) < 64u};

    int idx[8]; float w[8];
    int q = 0;
    #pragma unroll
    for (int dz = 0; dz < 2; ++dz)
        #pragma unroll
        for (int dy = 0; dy < 2; ++dy)
            #pragma unroll
            for (int dx = 0; dx < 2; ++dx) {
                idx[q] = zs[dz] * 2048 + ys[dy] * 64 + xs[dx];
                w[q] = (vx[dx] && vy[dy] && vz[dz]) ? wx[dx] * wy[dy] * wz[dz] : 0.0f;
                ++q;
            }

    const float* f1b = feat1 + (size_t)b * NCH * CHV;
    float* ob = outw + (size_t)b * NCH * CHV;
    #pragma unroll 1
    for (int c = 0; c < NCH; ++c) {
        const float* f1c = f1b + (size_t)c * CHV;
        float a = 0.0f;
        #pragma unroll
        for (int k = 0; k < 8; ++k) a += w[k] * f1c[idx[k]];
        ob[(size_t)c * CHV + p] = a;
    }
}

// ---------------------------------------------------------------------------
extern "C" void kernel_launch(void* const* d_in, const int* in_sizes, int n_in,
                              void* d_out, int out_size, void* d_ws, size_t ws_size,
                              hipStream_t stream)
{
    (void)in_sizes; (void)n_in; (void)out_size; (void)ws_size;
    const float* feat0 = (const float*)d_in[0];
    const float* feat1 = (const float*)d_in[1];
    const float* camg  = (const float*)d_in[2];
    const float* W1 = (const float*)d_in[3];
    const float* b1 = (const float*)d_in[4];
    const float* W2 = (const float*)d_in[5];
    const float* b2 = (const float*)d_in[6];
    const float* W3 = (const float*)d_in[7];
    const float* b3 = (const float*)d_in[8];
    float* out = (float*)d_out;

    float* partial = (float*)d_ws;                 // 12*128*2*27 floats ~ 332 KB
    float* params  = partial + 12 * NTI * 2 * 27;  // 32 floats

    hipLaunchKernelGGL(k_heat, dim3(1024), dim3(384), 0, stream,
                       feat0, feat1, partial);
    hipLaunchKernelGGL(k_mlp, dim3(1), dim3(256), 0, stream,
                       partial, camg, W1, b1, W2, b2, W3, b3, out, params);
    dim3 g3((64*32*64) / 256, NB);
    hipLaunchKernelGGL(k_warp, g3, dim3(256), 0, stream, feat1, params, out + 65);
}

// Round 8
// 238.937 us; speedup vs baseline: 3.2438x; 1.1017x over previous
//
#include <hip/hip_runtime.h>
#include <math.h>

#define NCH 32
#define CHV (64*32*64)      // one channel volume
#define NB 4
#define NT2 512             // tile-slots per n: 32zt * 8yt * 2chh
#define INVC (1.0f/(32.0f+1e-6f))
#define D2R 0.017453292519943295f
#define R2D 57.29577951308232f

// feat1 LDS slab: [8 z][4 y] rows, pitch 69 (odd mod 32 -> scalar bilinear
// reads ~2-way conflict-free). L[buf][0] is a zero guard (row0, bx=-1);
// col 68 of each row is a zero guard (bx=-1 of next row).
#define P1 69
#define BUFSZ (1 + 8*4*69 + 3)   // 2212 floats per buffer

// ---------------------------------------------------------------------------
// Kernel 1: fused rotate-warp(feat1) x 27-offset correlation vs feat0.
// Block = (b, chh, 2z x 4y x 64x tile): 256 threads.
// Wave 0 -> rot -4deg, wave 1 -> rot 0 (identity), wave 2 -> rot +4deg,
// wave 3 -> dedicated feat1 stager (double-buffered, 1 barrier/channel).
// feat0 rows are read DIRECT from global (coalesced b128; 3 waves share ->
// L1/L2 hits). x-edges via featN-extension (4 shuffles/ch, not 24/row).
// ---------------------------------------------------------------------------
__global__ __launch_bounds__(256) void k_heat(const float* __restrict__ feat0,
                                              const float* __restrict__ feat1,
                                              float* __restrict__ partial)
{
    __shared__ float L[2][BUFSZ];
    __shared__ float red[3][27];

    // XCD-chunked remap: XCD x gets 256 consecutive nids = exactly one (b,chh)
    const int lid = (int)blockIdx.x;            // 0..2047
    const int nid = (lid & 7) * 256 + (lid >> 3);
    const int yt  = nid & 7;
    const int zt  = (nid >> 3) & 31;
    const int chh = (nid >> 8) & 1;
    const int b   = nid >> 9;

    const int tid = (int)threadIdx.x;
    const int wv = tid >> 6;           // 0,1,2 compute; 3 stager
    const int lane = tid & 63;
    const int tx = lane & 15, ty = lane >> 4;
    const int x0 = 4 * tx;
    const int y  = 4 * yt + ty;
    const int z0 = 2 * zt;             // thread owns z0, z0+1

    // zero guards (both buffers): L[buf][0] + col-68 of 32 rows
    for (int i = tid; i < 66; i += 256) {
        const int bufi = i / 33, r = i - 33 * bufi;
        L[bufi][(r == 0) ? 0 : (1 + (r - 1) * P1 + 68)] = 0.0f;
    }

    const float* f0base = feat0 + ((size_t)b * NCH + chh * 16) * CHV;
    const float* f1base = feat1 + ((size_t)b * NCH + chh * 16) * CHV;

    // ---- stager setup: 544 float4 chunks = [8 z][4 y][17 chunk] ----
    int goff[9]; float gm[9]; int wof[9]; int wok[9];
    if (wv == 3) {
        #pragma unroll
        for (int k = 0; k < 9; ++k) {
            const int f = lane + 64 * k;
            const int zr = f / 68;
            const int fi = f - 68 * zr;
            const int yr = fi / 17;
            const int xq = (fi - 17 * yr) * 4;      // 0..64
            const int zs = 2 * zt - 3 + zr;
            const int ok = (f < 544) & (xq < 64) & (zs >= 0) & (zs < 64);
            goff[k] = ok ? (zs * 2048 + (4 * yt + yr) * 64 + xq) : 0;
            gm[k] = ok ? 1.0f : 0.0f;
            wof[k] = 1 + (zr * 4 + yr) * P1 + xq;
            wok[k] = (f < 544);
        }
    }

    // ---- bilinear setup (channel-invariant), rot waves 0/2 only ----
    float WX0[2][4], WX1[2][4], WZ0[2][4];
    int A[2][4];
    if (wv == 0 || wv == 2) {
        const float th = 4.0f * (float)(wv - 1) * D2R;
        const float cs = cosf(th), sn = sinf(th);
        #pragma unroll
        for (int k = 0; k < 2; ++k) {
            #pragma unroll
            for (int i = 0; i < 4; ++i) {
                const float rx = (float)(x0 + i) - 31.5f;
                const float rz = (float)(z0 + k) - 31.5f;
                const float sx = cs * rx - sn * rz + 31.5f;
                const float sz = sn * rx + cs * rz + 31.5f;
                const float xf = floorf(sx), zf = floorf(sz);
                const float fxv = sx - xf, fzv = sz - zf;
                const int ix = (int)xf, iz = (int)zf;
                WX0[k][i] = ((unsigned)ix < 64u) ? (1.0f - fxv) : 0.0f;
                WX1[k][i] = ((unsigned)(ix + 1) < 64u) ? fxv : 0.0f;
                WZ0[k][i] = 1.0f - fzv;     // z-OOB rows staged as zeros
                const int zl = min(max(iz - (2 * zt - 3), 0), 6);
                const int bx = min(max(ix, -1), 63);
                A[k][i] = 1 + (zl * 4 + ty) * P1 + bx;
            }
        }
    }
    const int iA0 = 1 + (3 * 4 + ty) * P1 + x0;      // identity: z0 row
    const int iA1 = 1 + (4 * 4 + ty) * P1 + x0;      // identity: z0+1 row

    // y-row masks + clamped offsets (channel-invariant, per lane)
    float myv[3]; int yoffc[3];
    #pragma unroll
    for (int yri = 0; yri < 3; ++yri) {
        const int yy = y - 1 + yri;
        myv[yri] = ((unsigned)yy < 32u) ? 1.0f : 0.0f;
        yoffc[yri] = min(max(yy, 0), 31) * 64;
    }

    float acc[27];
    #pragma unroll
    for (int o = 0; o < 27; ++o) acc[o] = 0.0f;

    // ---- prologue: stager loads+writes channel 0 into buffer 0 ----
    if (wv == 3) {
        float4 nv[9];
        #pragma unroll
        for (int k = 0; k < 9; ++k) nv[k] = *(const float4*)(f1base + goff[k]);
        #pragma unroll
        for (int k = 0; k < 9; ++k) if (wok[k]) {
            const float m = gm[k];
            L[0][wof[k] + 0] = nv[k].x * m; L[0][wof[k] + 1] = nv[k].y * m;
            L[0][wof[k] + 2] = nv[k].z * m; L[0][wof[k] + 3] = nv[k].w * m;
        }
    }
    __syncthreads();

    #pragma unroll 1
    for (int ch = 0; ch < 16; ++ch) {
        if (wv == 3) {
            // stage next channel into the other buffer
            if (ch + 1 < 16) {
                const float* f1c = f1base + (size_t)(ch + 1) * CHV;
                float4 nv[9];
                #pragma unroll
                for (int k = 0; k < 9; ++k) nv[k] = *(const float4*)(f1c + goff[k]);
                float* Ln = &L[(ch + 1) & 1][0];
                #pragma unroll
                for (int k = 0; k < 9; ++k) if (wok[k]) {
                    const float m = gm[k];
                    Ln[wof[k] + 0] = nv[k].x * m; Ln[wof[k] + 1] = nv[k].y * m;
                    Ln[wof[k] + 2] = nv[k].z * m; Ln[wof[k] + 3] = nv[k].w * m;
                }
            }
        } else {
            const float* Lb = &L[ch & 1][0];

            // ---- featN sample: fr[k][i] for owned voxels ----
            float fr[2][4];
            if (wv == 1) {                 // identity rotation
                #pragma unroll
                for (int i = 0; i < 4; ++i) {
                    fr[0][i] = Lb[iA0 + i];
                    fr[1][i] = Lb[iA1 + i];
                }
            } else {
                #pragma unroll
                for (int k = 0; k < 2; ++k) {
                    #pragma unroll
                    for (int i = 0; i < 4; ++i) {
                        const int a = A[k][i];
                        const float p00 = Lb[a], p01 = Lb[a + 1];
                        const float p10 = Lb[a + 4 * P1], p11 = Lb[a + 4 * P1 + 1];
                        const float w0 = WZ0[k][i];
                        const float t = p10 + w0 * (p00 - p10);
                        const float u = p11 + w0 * (p01 - p11);
                        fr[k][i] = WX0[k][i] * t + WX1[k][i] * u;
                    }
                }
            }

            // ---- featN x-extension (replaces per-row edge reads) ----
            float g0[2], g5[2];
            #pragma unroll
            for (int k = 0; k < 2; ++k) {
                const float a = __shfl_up(fr[k][3], 1, 64);
                const float c = __shfl_down(fr[k][0], 1, 64);
                g0[k] = (tx == 0) ? 0.0f : a;     // featN[x=-1] = 0 (pad)
                g5[k] = (tx == 15) ? 0.0f : c;    // featN[x=64] = 0 (pad)
            }

            // ---- correlation: 12 feat0 rows direct from global ----
            const float* f0c = f0base + (size_t)ch * CHV;
#define ROWFMA(KK, OZP1, YRI)                                                   \
            { const int base_ = (OZP1) * 9 + (2 - (YRI)) * 3;                   \
              acc[base_ + 0] += g0[KK]*R.x + fr[KK][0]*R.y + fr[KK][1]*R.z + fr[KK][2]*R.w; \
              acc[base_ + 1] += fr[KK][0]*R.x + fr[KK][1]*R.y + fr[KK][2]*R.z + fr[KK][3]*R.w; \
              acc[base_ + 2] += fr[KK][1]*R.x + fr[KK][2]*R.y + fr[KK][3]*R.z + g5[KK]*R.w; }
            #pragma unroll
            for (int zri = 0; zri < 4; ++zri) {
                const int zz = 2 * zt - 1 + zri;
                if (zz >= 0 && zz <= 63) {             // block-uniform
                    const float* rp = f0c + zz * 2048;
                    #pragma unroll
                    for (int yri = 0; yri < 3; ++yri) {
                        float4 R = *(const float4*)(rp + yoffc[yri] + x0);
                        const float m = myv[yri];
                        R.x *= m; R.y *= m; R.z *= m; R.w *= m;
                        if (zri == 0) { ROWFMA(0, 2, yri) }
                        if (zri == 1) { ROWFMA(0, 1, yri) ROWFMA(1, 2, yri) }
                        if (zri == 2) { ROWFMA(0, 0, yri) ROWFMA(1, 1, yri) }
                        if (zri == 3) { ROWFMA(1, 0, yri) }
                    }
                }
            }
#undef ROWFMA
        }
        __syncthreads();
    }

    // ---- per-wave reduction (fixed order -> deterministic) ----
    if (wv < 3) {
        #pragma unroll 1
        for (int o = 0; o < 27; ++o) {
            float v = acc[o];
            #pragma unroll
            for (int d = 32; d >= 1; d >>= 1) v += __shfl_down(v, d, 64);
            if (lane == 0) red[wv][o] = v;
        }
    }
    __syncthreads();
    if (tid < 81) {
        const int rr = tid / 27, o = tid - rr * 27;
        const int slot = (zt * 8 + yt) * 2 + chh;
        partial[((size_t)((b * 3 + rr) * 27) + o) * NT2 + slot] = red[rr][o];
    }
}

// ---------------------------------------------------------------------------
// Kernel 2: reduce partials (transposed layout: [n*27][512] rows, vectorized)
// -> heat, per-batch MLP, loss + matrices + params.
// ---------------------------------------------------------------------------
__global__ __launch_bounds__(256) void k_mlp(const float* __restrict__ partial,
                                             const float* __restrict__ camg,
                                             const float* __restrict__ W1,
                                             const float* __restrict__ b1,
                                             const float* __restrict__ W2,
                                             const float* __restrict__ b2,
                                             const float* __restrict__ W3,
                                             const float* __restrict__ b3,
                                             float* __restrict__ out,
                                             float* __restrict__ params)
{
    __shared__ float heat[324];
    __shared__ float f[81];
    __shared__ float h1[128];
    __shared__ float h2[128];
    __shared__ float denom_s;
    __shared__ float res[NB][8];
    const int tid = (int)threadIdx.x;

    for (int r = tid; r < 324; r += 256) {
        const float4* p = (const float4*)(partial + (size_t)r * NT2);
        float s0 = 0.0f, s1 = 0.0f, s2 = 0.0f, s3 = 0.0f;
        #pragma unroll 4
        for (int i = 0; i < NT2 / 4; ++i) {
            const float4 v = p[i];
            s0 += v.x; s1 += v.y; s2 += v.z; s3 += v.w;
        }
        heat[r] = ((s0 + s1) + (s2 + s3)) * INVC;
    }
    __syncthreads();

    for (int b = 0; b < NB; ++b) {
        if (tid < 81) {
            float v = heat[b * 81 + tid];
            f[tid] = (v >= 0.0f) ? v : 0.1f * v;
        }
        __syncthreads();
        if (tid == 0) {
            float ss = 0.0f;
            for (int k = 0; k < 81; ++k) ss += f[k] * f[k];
            denom_s = 1e-6f + sqrtf(ss);
        }
        __syncthreads();
        if (tid < 81) f[tid] = f[tid] / denom_s;
        __syncthreads();
        if (tid < 128) {
            float a = b1[tid];
            const float* wr = W1 + tid * 81;
            for (int k = 0; k < 81; ++k) a += wr[k] * f[k];
            h1[tid] = (a >= 0.0f) ? a : 0.1f * a;
        }
        __syncthreads();
        if (tid < 128) {
            float a = b2[tid];
            const float* wr = W2 + tid * 128;
            for (int k = 0; k < 128; ++k) a += wr[k] * h1[k];
            h2[tid] = (a >= 0.0f) ? a : 0.1f * a;
        }
        __syncthreads();
        if (tid < 4) {
            float a = b3[tid];
            const float* wr = W3 + tid * 128;
            for (int k = 0; k < 128; ++k) a += wr[k] * h2[k];
            res[b][4 + tid] = a;
        }
        __syncthreads();
        if (tid == 0) {
            const float r_out = res[b][4], yv = res[b][5], xv = res[b][6], zv = res[b][7];
            const float t2 = r_out * D2R;
            const float c2 = cosf(t2), s2 = sinf(t2);
            float* m = out + 1 + b * 16;
            m[0] = c2;  m[1] = 0.0f; m[2] = s2;  m[3] = -xv;
            m[4] = 0.0f; m[5] = 1.0f; m[6] = 0.0f; m[7] = -yv;
            m[8] = -s2; m[9] = 0.0f; m[10] = c2; m[11] = -zv;
            m[12] = 0.0f; m[13] = 0.0f; m[14] = 0.0f; m[15] = 1.0f;
            params[b * 8 + 0] = c2;
            params[b * 8 + 1] = s2;
            params[b * 8 + 2] = c2 * xv - s2 * zv;
            params[b * 8 + 3] = yv;
            params[b * 8 + 4] = s2 * xv + c2 * zv;
            res[b][0] = -xv; res[b][1] = -yv; res[b][2] = -zv;
            res[b][3] = atan2f(s2, c2) * R2D;
        }
        __syncthreads();
    }

    if (tid == 0) {
        float tl2 = 0.0f, dl2 = 0.0f;
        for (int b = 0; b < NB; ++b) {
            const float* g = camg + b * 16;
            const float dx = res[b][0] - g[3];
            const float dy = res[b][1] - g[7];
            const float dz = res[b][2] - g[11];
            tl2 += dx * dx + dy * dy + dz * dz;
            const float dg = atan2f(g[2], g[10]) * R2D;
            const float dd = res[b][3] - dg;
            dl2 += dd * dd;
        }
        out[0] = tl2 * 0.25f + dl2 * 0.25f;
    }
}

// ---------------------------------------------------------------------------
// Kernel 3: warp feat1 by estimated transform -> feat1_warped (d_out + 65).
// ---------------------------------------------------------------------------
__global__ __launch_bounds__(256) void k_warp(const float* __restrict__ feat1,
                                              const float* __restrict__ params,
                                              float* __restrict__ outw)
{
    const int b = blockIdx.y;
    const int p = (int)blockIdx.x * 256 + (int)threadIdx.x;
    const int z = p >> 11;
    const int y = (p >> 6) & 31;
    const int x = p & 63;

    const float cs = params[b * 8 + 0], sn = params[b * 8 + 1];
    const float tpx = params[b * 8 + 2], tpy = params[b * 8 + 3], tpz = params[b * 8 + 4];

    const float rx = (float)x - 31.5f;
    const float ry = (float)y - 15.5f;
    const float rz = (float)z - 31.5f;
    const float sx = cs * rx - sn * rz + tpx + 31.5f;
    const float sy = ry + tpy + 15.5f;
    const float sz = sn * rx + cs * rz + tpz + 31.5f;

    const float xf = floorf(sx), yf = floorf(sy), zf = floorf(sz);
    const float fx = sx - xf, fy = sy - yf, fz = sz - zf;
    const int ix = (int)xf, iy = (int)yf, iz = (int)zf;

    const float wx[2] = {1.0f - fx, fx};
    const float wy[2] = {1.0f - fy, fy};
    const float wz[2] = {1.0f - fz, fz};
    const int xs[2] = {min(max(ix, 0), 63), min(max(ix + 1, 0), 63)};
    const int ys[2] = {min(max(iy, 0), 31), min(max(iy + 1, 0), 31)};
    const int zs[2] = {min(max(iz, 0), 63), min(max(iz + 1, 0), 63)};
    const bool vx[2] = {(unsigned)ix < 64u, (unsigned)(ix + 1) < 64u};
    const bool vy[2] = {(unsigned)iy < 32u, (unsigned)(iy + 1) < 32u};
    const bool vz[2] = {(unsigned)iz < 64u, (unsigned)(iz + 1) < 64u};

    int idx[8]; float w[8];
    int q = 0;
    #pragma unroll
    for (int dz = 0; dz < 2; ++dz)
        #pragma unroll
        for (int dy = 0; dy < 2; ++dy)
            #pragma unroll
            for (int dx = 0; dx < 2; ++dx) {
                idx[q] = zs[dz] * 2048 + ys[dy] * 64 + xs[dx];
                w[q] = (vx[dx] && vy[dy] && vz[dz]) ? wx[dx] * wy[dy] * wz[dz] : 0.0f;
                ++q;
            }

    const float* f1b = feat1 + (size_t)b * NCH * CHV;
    float* ob = outw + (size_t)b * NCH * CHV;
    #pragma unroll 1
    for (int c = 0; c < NCH; ++c) {
        const float* f1c = f1b + (size_t)c * CHV;
        float a = 0.0f;
        #pragma unroll
        for (int k = 0; k < 8; ++k) a += w[k] * f1c[idx[k]];
        ob[(size_t)c * CHV + p] = a;
    }
}

// ---------------------------------------------------------------------------
extern "C" void kernel_launch(void* const* d_in, const int* in_sizes, int n_in,
                              void* d_out, int out_size, void* d_ws, size_t ws_size,
                              hipStream_t stream)
{
    (void)in_sizes; (void)n_in; (void)out_size; (void)ws_size;
    const float* feat0 = (const float*)d_in[0];
    const float* feat1 = (const float*)d_in[1];
    const float* camg  = (const float*)d_in[2];
    const float* W1 = (const float*)d_in[3];
    const float* b1 = (const float*)d_in[4];
    const float* W2 = (const float*)d_in[5];
    const float* b2 = (const float*)d_in[6];
    const float* W3 = (const float*)d_in[7];
    const float* b3 = (const float*)d_in[8];
    float* out = (float*)d_out;

    float* partial = (float*)d_ws;                 // 324*512 floats ~ 663 KB
    float* params  = partial + 324 * NT2;          // 32 floats

    hipLaunchKernelGGL(k_heat, dim3(2048), dim3(256), 0, stream,
                       feat0, feat1, partial);
    hipLaunchKernelGGL(k_mlp, dim3(1), dim3(256), 0, stream,
                       partial, camg, W1, b1, W2, b2, W3, b3, out, params);
    dim3 g3((64*32*64) / 256, NB);
    hipLaunchKernelGGL(k_warp, g3, dim3(256), 0, stream, feat1, params, out + 65);
}